// Round 16
// baseline (104.896 us; speedup 1.0000x reference)
//
#include <hip/hip_runtime.h>
#include <math.h>
#include <stdint.h>

#define SEQ 2048
#define DM  1024
#define NH  16
#define HD  64
#define TRI 3072  // 3*DM
#define NSPLIT 4  // KV-split factor

typedef _Float16 half8 __attribute__((ext_vector_type(8)));
typedef __fp16 fp16x2 __attribute__((ext_vector_type(2)));
typedef float f32x4 __attribute__((ext_vector_type(4)));

// global -> LDS direct 16B copy. LDS dest is wave-uniform base; HW adds lane*16.
#define GLOAD_LDS16(g, l)                                       \
  __builtin_amdgcn_global_load_lds(                             \
      (__attribute__((address_space(1))) void*)(g),             \
      (__attribute__((address_space(3))) void*)(l), 16, 0, 0)

// q pre-scale: 1/sqrt(64) * 1/ln(2)  (softmax runs in exp2 domain)
#define QSCALE 0.18033688011112042f

// ---------------------------------------------------------------------------
// fp32 -> fp16 conversion (query/qkv_w/out_w) + RoPE cos/sin table fill.
// ---------------------------------------------------------------------------
__global__ __launch_bounds__(256)
void cvt3(const float* __restrict__ s1, const float* __restrict__ s2,
          const float* __restrict__ s3, _Float16* __restrict__ d1,
          _Float16* __restrict__ d2, _Float16* __restrict__ d3,
          float2* __restrict__ tab, int n1, int n2) {
  int b = blockIdx.x;
  if (b >= 6144) {
    int i = (b - 6144) * 256 + threadIdx.x;     // 0..65535 -> (s, d)
    int s = i >> 5, d = i & 31;
    float inv = exp2f((float)d * -0.4152410118609203f);  // theta^(-d/32)
    float ang = (float)s * inv;
    float sn, cs;
    sincosf(ang, &sn, &cs);
    tab[i] = make_float2(cs, sn);
    return;
  }
  int i = (b * 256 + threadIdx.x) * 4;
  const float* s; _Float16* d;
  if (i < n1)            { s = s1; d = d1; }
  else if (i < n1 + n2)  { s = s2; d = d2; i -= n1; }
  else                   { s = s3; d = d3; i -= n1 + n2; }
  float4 v = *(const float4*)(s + i);
  union { _Float16 h[4]; uint2 u; } pk;
  pk.h[0] = (_Float16)v.x; pk.h[1] = (_Float16)v.y;
  pk.h[2] = (_Float16)v.z; pk.h[3] = (_Float16)v.w;
  *(uint2*)(d + i) = pk.u;
}

// ---------------------------------------------------------------------------
// QKV GEMM: 128x128 tile, BK=32, 3-buffer LDS pipeline, counted vmcnt(4),
// one raw barrier per k-step. Epilogue: rope q (row-major, QSCALE), rope k
// (row-major), V transposed tile-major swizzled.
// ---------------------------------------------------------------------------
__global__ __launch_bounds__(256)
void gemm_qkv(const _Float16* __restrict__ A, const _Float16* __restrict__ B,
              const float* __restrict__ bias, const float2* __restrict__ tab,
              _Float16* __restrict__ Qo, _Float16* __restrict__ Ko,
              _Float16* __restrict__ Vo) {
  constexpr int K = DM;
  __shared__ _Float16 As[3][128 * 32];
  __shared__ _Float16 Bs[3][128 * 32];

  const int t = threadIdx.x, lane = t & 63, wv = t >> 6;
  const int l15 = lane & 15, l4 = lane >> 4;
  const int wr = wv >> 1, wc = wv & 1;
  const int bm = blockIdx.y * 128, bn = blockIdx.x * 128;

  auto stage = [&](int buf, int k0) {
    #pragma unroll
    for (int i = 0; i < 2; ++i) {
      int c = t + i * 256;
      GLOAD_LDS16(A + (size_t)(bm + (c >> 2)) * K + k0 + (c & 3) * 8,
                  (char*)&As[buf][(i * 256 + wv * 64) * 8]);
    }
    #pragma unroll
    for (int i = 0; i < 2; ++i) {
      int c = t + i * 256;
      GLOAD_LDS16(B + (size_t)(bn + (c >> 2)) * K + k0 + (c & 3) * 8,
                  (char*)&Bs[buf][(i * 256 + wv * 64) * 8]);
    }
  };

  f32x4 acc[4][4] = {};
  stage(0, 0);
  stage(1, 32);

  const int nk = K / 32;
  for (int s = 0; s < nk; ++s) {
    int cur = s % 3;
    if (s + 1 < nk) asm volatile("s_waitcnt vmcnt(4)" ::: "memory");
    else            asm volatile("s_waitcnt vmcnt(0)" ::: "memory");
    __builtin_amdgcn_s_barrier();
    __builtin_amdgcn_sched_barrier(0);
    if (s + 2 < nk) stage((s + 2) % 3, (s + 2) * 32);

    half8 af[4], bf[4];
    #pragma unroll
    for (int mf = 0; mf < 4; ++mf)
      af[mf] = *(const half8*)&As[cur][(wr * 64 + mf * 16 + l15) * 32 + l4 * 8];
    #pragma unroll
    for (int nf = 0; nf < 4; ++nf)
      bf[nf] = *(const half8*)&Bs[cur][(wc * 64 + nf * 16 + l15) * 32 + l4 * 8];
    __builtin_amdgcn_s_setprio(1);
    #pragma unroll
    for (int mf = 0; mf < 4; ++mf)
      #pragma unroll
      for (int nf = 0; nf < 4; ++nf)
        acc[mf][nf] = __builtin_amdgcn_mfma_f32_16x16x32_f16(
            af[mf], bf[nf], acc[mf][nf], 0, 0, 0);
    __builtin_amdgcn_s_setprio(0);
  }

  const int sec = bn >> 10;  // 0=q, 1=k, 2=v
  float bv[4];
  #pragma unroll
  for (int nf = 0; nf < 4; ++nf) bv[nf] = bias[bn + wc * 64 + nf * 16 + l15];

  if (sec < 2) {
    _Float16* dst = (sec == 0) ? Qo : Ko;
    #pragma unroll
    for (int mf = 0; mf < 4; ++mf)
      #pragma unroll
      for (int r = 0; r < 4; ++r) {
        int row = bm + wr * 64 + mf * 16 + l4 * 4 + r;
        float v0 = acc[mf][0][r] + bv[0];
        float v1 = acc[mf][1][r] + bv[1];
        float v2 = acc[mf][2][r] + bv[2];
        float v3 = acc[mf][3][r] + bv[3];
        float2 cs0 = tab[row * 32 + l15];
        float2 cs1 = tab[row * 32 + 16 + l15];
        float a0 = v0 * cs0.x - v2 * cs0.y;
        float a2 = v2 * cs0.x + v0 * cs0.y;
        float a1 = v1 * cs1.x - v3 * cs1.y;
        float a3 = v3 * cs1.x + v1 * cs1.y;
        if (sec == 0) { a0 *= QSCALE; a1 *= QSCALE; a2 *= QSCALE; a3 *= QSCALE; }
        _Float16* cr = dst + (size_t)row * DM + (bn & 1023) + wc * 64 + l15;
        cr[0]  = (_Float16)a0; cr[16] = (_Float16)a1;
        cr[32] = (_Float16)a2; cr[48] = (_Float16)a3;
      }
  } else {
    // V: transposed tile-major swizzled [h][kseg][d][chunk^(d&7)][8]
    const int hh = ((bn - 2048) >> 6) + wc;
    #pragma unroll
    for (int mf = 0; mf < 4; ++mf) {
      int row0 = bm + wr * 64 + mf * 16 + l4 * 4;
      int kk0 = row0 & 63, kseg = row0 >> 6;
      #pragma unroll
      for (int nf = 0; nf < 4; ++nf) {
        int d = nf * 16 + l15;
        union { _Float16 hh4[4]; uint2 u; } pk;
        #pragma unroll
        for (int r = 0; r < 4; ++r)
          pk.hh4[r] = (_Float16)(acc[mf][nf][r] + bv[nf]);
        size_t off = ((size_t)(hh * 32 + kseg) * 64 + d) * 64 +
                     (((kk0 >> 3) ^ (d & 7)) * 8) + (kk0 & 7);
        *(uint2*)(Vo + off) = pk.u;
      }
    }
  }
}

// ---------------------------------------------------------------------------
// MFMA flash attention (R14 config: 8 waves / 128 q-rows / block, 1 q-group
// per wave). All-x32 permuted-key pipeline: packed exp2(P) registers feed
// 16x16x32 PV directly. Max-free exp2 softmax; pure-DMA double-buffered K/V;
// one barrier per tile; DMA issued after the barrier.
// ---------------------------------------------------------------------------
__global__ __launch_bounds__(512)
void attn_f16(const _Float16* __restrict__ Qg, const _Float16* __restrict__ Kg,
              const _Float16* __restrict__ Vg, _Float16* __restrict__ poA,
              _Float16* __restrict__ po3, float* __restrict__ pl) {
  __shared__ _Float16 Kl[2][64 * 64];   // [kk][chunk p at p^HK(kk)]
  __shared__ _Float16 Vt[2][64 * 64];   // [d][chunk p at p^(d&7)]

  const int t = threadIdx.x, lane = t & 63, wv = t >> 6;  // wv in 0..7
  const int l15 = lane & 15, l4 = lane >> 4;
  const int bid = blockIdx.x;
  const int c = bid & 63, qb = bid >> 6;   // same (h,z) => same XCD (64%8==0)
  const int h = c & 15, z = c >> 4;        // z in 0..3
  const int q0 = qb * 128;
  const int seg0 = z * (SEQ / NSPLIT / 64);

  const _Float16* Qp = Qg + h * HD;
  const _Float16* Kp = Kg + h * HD;                 // row-major [s][1024]
  const _Float16* Vbase = Vg + (size_t)h * 32 * 4096;

  half8 qf[2];
  {
    const _Float16* qrow = Qp + (size_t)(q0 + wv * 16 + l15) * DM;
    qf[0] = *(const half8*)(qrow + l4 * 8);
    qf[1] = *(const half8*)(qrow + 32 + l4 * 8);
  }

  // per-lane K source offset: chunk c=t -> row kk=t>>3, p=t&7,
  // src col chunk = p ^ HK(kk), HK = bits{0,1,3} of kk
  int koff;
  {
    int kk = t >> 3, p = t & 7;
    int hkk = (kk & 3) | ((kk >> 1) & 4);
    koff = kk * DM + ((p ^ hkk) * 8);
  }

  auto issueKV = [&](int buf, int seg) {
    const _Float16* ks = Kp + (size_t)seg * 64 * DM;
    const _Float16* vs = Vbase + (size_t)seg * 4096;
    GLOAD_LDS16(ks + koff,          (char*)&Kl[buf][(wv * 64) * 8]);
    GLOAD_LDS16(vs + (size_t)t * 8, (char*)&Vt[buf][(wv * 64) * 8]);
  };

  f32x4 lacc = {0.f, 0.f, 0.f, 0.f};
  f32x4 o[4] = {};   // O^T: o[nf][r] = O[d = nf*16 + l4*4 + r][q = l15]

  const int hk = (l15 & 3) | (((l15 >> 2) & 1) << 2);  // HK(kappa), m-indep
  const int krow = 8 * (l15 >> 2) + (l15 & 3);         // kappa_m base

  issueKV(0, seg0);

  const int NT = SEQ / NSPLIT / 64;
  #pragma unroll 2
  for (int tt = 0; tt < NT; ++tt) {
    const int cur = tt & 1;
    asm volatile("s_waitcnt vmcnt(0)" ::: "memory");
    __builtin_amdgcn_s_barrier();
    __builtin_amdgcn_sched_barrier(0);
    if (tt + 1 < NT) issueKV(cur ^ 1, seg0 + tt + 1);  // covered by compute(t)

    // S^T = K . Q^T with permuted key rows (exp2 domain)
    f32x4 sT[4] = {};
    __builtin_amdgcn_s_setprio(1);
    #pragma unroll
    for (int ds = 0; ds < 2; ++ds)
      #pragma unroll
      for (int m = 0; m < 4; ++m) {
        int kappa = 32 * (m >> 1) + 4 * (m & 1) + krow;
        int cb = ds * 4 + l4;
        half8 kf = *(const half8*)((char*)Kl[cur] + kappa * 128 +
                                   ((cb ^ hk) * 16));
        sT[m] = __builtin_amdgcn_mfma_f32_16x16x32_f16(kf, qf[ds], sT[m], 0, 0, 0);
      }
    __builtin_amdgcn_s_setprio(0);

    // P = exp2(S); packed pairs form the PV B-frags directly
    half8 pB[2];
    #pragma unroll
    for (int s2 = 0; s2 < 2; ++s2) {
      union { fp16x2 h2[4]; half8 v; } pu;
      #pragma unroll
      for (int mh = 0; mh < 2; ++mh) {
        int m = s2 * 2 + mh;
        f32x4 p;
        #pragma unroll
        for (int r = 0; r < 4; ++r) p[r] = exp2f(sT[m][r]);
        lacc += p;
        pu.h2[mh * 2 + 0] = __builtin_amdgcn_cvt_pkrtz(p[0], p[1]);
        pu.h2[mh * 2 + 1] = __builtin_amdgcn_cvt_pkrtz(p[2], p[3]);
      }
      pB[s2] = pu.v;
    }

    // PV: O^T[d][q] += V^T[d][k] . P[k][q], 16x16x32, b128 V reads
    __builtin_amdgcn_s_setprio(1);
    #pragma unroll
    for (int s2 = 0; s2 < 2; ++s2)
      #pragma unroll
      for (int nf = 0; nf < 4; ++nf) {
        half8 va = *(const half8*)((char*)Vt[cur] + (nf * 16 + l15) * 128 +
                                   (((s2 * 4 + l4) ^ (l15 & 7)) * 16));
        o[nf] = __builtin_amdgcn_mfma_f32_16x16x32_f16(va, pB[s2], o[nf], 0, 0, 0);
      }
    __builtin_amdgcn_s_setprio(0);
  }

  // epilogue: unnormalized partial O (transposed acc -> row=q stores) + l
  float lv = (lacc[0] + lacc[1]) + (lacc[2] + lacc[3]);
  lv += __shfl_xor(lv, 16);
  lv += __shfl_xor(lv, 32);
  _Float16* pz = (z < 3) ? (poA + (size_t)z * SEQ * DM) : po3;
  {
    int row = q0 + wv * 16 + l15;
    _Float16* pr = pz + (size_t)row * DM + h * HD + l4 * 4;
    #pragma unroll
    for (int nf = 0; nf < 4; ++nf) {
      union { fp16x2 h2[2]; uint2 u; } ou;
      ou.h2[0] = __builtin_amdgcn_cvt_pkrtz(o[nf][0], o[nf][1]);
      ou.h2[1] = __builtin_amdgcn_cvt_pkrtz(o[nf][2], o[nf][3]);
      *(uint2*)(pr + nf * 16) = ou.u;
    }
  }
  if (l4 == 0) {
    int q = q0 + wv * 16 + l15;
    pl[(z * NH + h) * SEQ + q] = lv;
  }
}

// ---------------------------------------------------------------------------
// Output GEMM with FUSED 4-way flash-combine: A[s][c] = (Sum_z po_z[s][c]) *
// invL[s][c>>6], built on the fly in reg-staged A tiles (every 32-wide A
// chunk lies within one head since k-step=32 < head width 64). invL table
// (64 rows x 16 heads) built once per block in LDS. B via gload_lds,
// 2-buffer + __syncthreads. Deletes the merge kernel + ctx round-trip.
// ---------------------------------------------------------------------------
__global__ __launch_bounds__(256)
void gemm_out_merge(const _Float16* __restrict__ poA,
                    const _Float16* __restrict__ po3,
                    const float* __restrict__ pl,
                    const _Float16* __restrict__ Bw,
                    const float* __restrict__ bias,
                    float* __restrict__ C) {
  constexpr int K = DM, N = DM;
  __shared__ _Float16 As[2][64 * 32];
  __shared__ _Float16 Bs[2][128 * 32];
  __shared__ float Ls[64 * 16];   // invL[row][head]

  const int t = threadIdx.x, lane = t & 63, wv = t >> 6;
  const int l15 = lane & 15, l4 = lane >> 4;
  const int wr = wv >> 1, wc = wv & 1;
  const int bm = blockIdx.y * 64, bn = blockIdx.x * 128;

  auto stageB = [&](int buf, int k0) {
    #pragma unroll
    for (int i = 0; i < 2; ++i) {
      int c = t + i * 256;
      GLOAD_LDS16(Bw + (size_t)(bn + (c >> 2)) * K + k0 + (c & 3) * 8,
                  (char*)&Bs[buf][(i * 256 + wv * 64) * 8]);
    }
  };

  const int arow = t >> 2;                 // A row 0..63
  const size_t abase = (size_t)(bm + arow) * DM + (t & 3) * 8;

  half8 a0, a1, a2, a3;
  auto loadA = [&](int k0) {
    const _Float16* p = poA + abase + k0;
    a0 = *(const half8*)p;
    a1 = *(const half8*)(p + (size_t)SEQ * DM);
    a2 = *(const half8*)(p + 2 * (size_t)SEQ * DM);
    a3 = *(const half8*)(po3 + abase + k0);
  };
  auto writeA = [&](int buf, int k0) {
    float inv = Ls[arow * 16 + (k0 >> 6)];
    union { fp16x2 h2[4]; half8 v; } m;
    #pragma unroll
    for (int j = 0; j < 4; ++j) {
      float lo = ((float)a0[2 * j] + (float)a1[2 * j] +
                  (float)a2[2 * j] + (float)a3[2 * j]) * inv;
      float hi = ((float)a0[2 * j + 1] + (float)a1[2 * j + 1] +
                  (float)a2[2 * j + 1] + (float)a3[2 * j + 1]) * inv;
      m.h2[j] = __builtin_amdgcn_cvt_pkrtz(lo, hi);
    }
    *(half8*)((char*)As[buf] + t * 16) = m.v;
  };

  // prologue: invL table + first stages
  stageB(0, 0);
  #pragma unroll
  for (int i = 0; i < 4; ++i) {
    int e = t + i * 256;                  // (row, head)
    int row = e >> 4, hh = e & 15;
    int s = bm + row;
    float L = pl[hh * SEQ + s] + pl[(NH + hh) * SEQ + s] +
              pl[(2 * NH + hh) * SEQ + s] + pl[(3 * NH + hh) * SEQ + s];
    Ls[e] = 1.0f / L;
  }
  loadA(0);
  __syncthreads();        // Ls visible (also drains first B DMA; acceptable)
  writeA(0, 0);
  __syncthreads();        // As[0] visible

  f32x4 acc[2][4] = {};
  const int nk = K / 32;
  for (int s = 0; s < nk; ++s) {
    int cur = s & 1;
    if (s + 1 < nk) { stageB(cur ^ 1, (s + 1) * 32); loadA((s + 1) * 32); }

    half8 af[2], bf[4];
    #pragma unroll
    for (int mf = 0; mf < 2; ++mf)
      af[mf] = *(const half8*)&As[cur][(wr * 32 + mf * 16 + l15) * 32 + l4 * 8];
    #pragma unroll
    for (int nf = 0; nf < 4; ++nf)
      bf[nf] = *(const half8*)&Bs[cur][(wc * 64 + nf * 16 + l15) * 32 + l4 * 8];
    __builtin_amdgcn_s_setprio(1);
    #pragma unroll
    for (int mf = 0; mf < 2; ++mf)
      #pragma unroll
      for (int nf = 0; nf < 4; ++nf)
        acc[mf][nf] = __builtin_amdgcn_mfma_f32_16x16x32_f16(
            af[mf], bf[nf], acc[mf][nf], 0, 0, 0);
    __builtin_amdgcn_s_setprio(0);

    if (s + 1 < nk) writeA(cur ^ 1, (s + 1) * 32);  // write-late (T14)
    __syncthreads();   // drains B DMA + A ds_writes; buffers swap safely
  }

  float bv[4];
  #pragma unroll
  for (int nf = 0; nf < 4; ++nf) bv[nf] = bias[bn + wc * 64 + nf * 16 + l15];
  #pragma unroll
  for (int mf = 0; mf < 2; ++mf)
    #pragma unroll
    for (int r = 0; r < 4; ++r) {
      int row = bm + wr * 32 + mf * 16 + l4 * 4 + r;
      float* cr = C + (size_t)row * N + bn + wc * 64 + l15;
      cr[0]  = acc[mf][0][r] + bv[0];
      cr[16] = acc[mf][1][r] + bv[1];
      cr[32] = acc[mf][2][r] + bv[2];
      cr[48] = acc[mf][3][r] + bv[3];
    }
}

// ---------------------------------------------------------------------------
extern "C" void kernel_launch(void* const* d_in, const int* in_sizes, int n_in,
                              void* d_out, int out_size, void* d_ws, size_t ws_size,
                              hipStream_t stream) {
  const float* query = (const float*)d_in[0];
  const float* qkv_w = (const float*)d_in[3];
  const float* qkv_b = (const float*)d_in[4];
  const float* out_w = (const float*)d_in[5];
  const float* out_b = (const float*)d_in[6];
  float* out = (float*)d_out;

  char* ws = (char*)d_ws;
  _Float16* Aq   = (_Float16*)ws;                       // [0, 4 MiB)   dead after qkv
  _Float16* Wqkv = (_Float16*)(ws + (4u << 20));        // [4, 10 MiB)  dead after qkv
  _Float16* Qb   = (_Float16*)(ws + (12u << 20));       // [12, 16 MiB)
  _Float16* Kb   = (_Float16*)(ws + (16u << 20));       // [16, 20 MiB) row-major roped
  _Float16* Vb   = (_Float16*)(ws + (20u << 20));       // [20, 24 MiB) tile-major
  _Float16* po3  = (_Float16*)(ws + (24u << 20));       // [24, 28 MiB) partial z=3
  float2*   tab  = (float2*)(ws + (28u << 20));         // [28, 28.5 MiB)
  _Float16* Wout = (_Float16*)(ws + (28u << 20) + (512u << 10)); // [28.5, 30.5)
  float*    pl   = (float*)(ws + (30u << 20) + (512u << 10));    // [30.5, 31)
  // partials z=0..2 in the dead Aq/Wqkv region after the QKV GEMM:
  _Float16* poA  = (_Float16*)ws;                       // [0, 12 MiB)

  cvt3<<<6400, 256, 0, stream>>>(query, qkv_w, out_w, Aq, Wqkv, Wout, tab,
                                 SEQ * DM, TRI * DM);

  gemm_qkv<<<dim3(TRI / 128, SEQ / 128), 256, 0, stream>>>(
      Aq, Wqkv, qkv_b, tab, Qb, Kb, Vb);

  attn_f16<<<(SEQ / 128) * NH * NSPLIT, 512, 0, stream>>>(
      Qb, Kb, Vb, poA, po3, pl);

  gemm_out_merge<<<dim3(DM / 128, SEQ / 64), 256, 0, stream>>>(
      poA, po3, pl, Wout, out_b, out);
}

// Round 17
// 92.593 us; speedup vs baseline: 1.1329x; 1.1329x over previous
//
#include <hip/hip_runtime.h>
#include <math.h>
#include <stdint.h>

#define SEQ 2048
#define DM  1024
#define NH  16
#define HD  64
#define TRI 3072  // 3*DM
#define NSPLIT 4  // KV-split factor

typedef _Float16 half8 __attribute__((ext_vector_type(8)));
typedef __fp16 fp16x2 __attribute__((ext_vector_type(2)));
typedef float f32x4 __attribute__((ext_vector_type(4)));

// global -> LDS direct 16B copy. LDS dest is wave-uniform base; HW adds lane*16.
#define GLOAD_LDS16(g, l)                                       \
  __builtin_amdgcn_global_load_lds(                             \
      (__attribute__((address_space(1))) void*)(g),             \
      (__attribute__((address_space(3))) void*)(l), 16, 0, 0)

// q pre-scale: 1/sqrt(64) * 1/ln(2)  (softmax runs in exp2 domain)
#define QSCALE 0.18033688011112042f

// ---------------------------------------------------------------------------
// fp32 -> fp16 conversion (query/qkv_w/out_w) + RoPE cos/sin table fill.
// ---------------------------------------------------------------------------
__global__ __launch_bounds__(256)
void cvt3(const float* __restrict__ s1, const float* __restrict__ s2,
          const float* __restrict__ s3, _Float16* __restrict__ d1,
          _Float16* __restrict__ d2, _Float16* __restrict__ d3,
          float2* __restrict__ tab, int n1, int n2) {
  int b = blockIdx.x;
  if (b >= 6144) {
    int i = (b - 6144) * 256 + threadIdx.x;     // 0..65535 -> (s, d)
    int s = i >> 5, d = i & 31;
    float inv = exp2f((float)d * -0.4152410118609203f);  // theta^(-d/32)
    float ang = (float)s * inv;
    float sn, cs;
    sincosf(ang, &sn, &cs);
    tab[i] = make_float2(cs, sn);
    return;
  }
  int i = (b * 256 + threadIdx.x) * 4;
  const float* s; _Float16* d;
  if (i < n1)            { s = s1; d = d1; }
  else if (i < n1 + n2)  { s = s2; d = d2; i -= n1; }
  else                   { s = s3; d = d3; i -= n1 + n2; }
  float4 v = *(const float4*)(s + i);
  union { _Float16 h[4]; uint2 u; } pk;
  pk.h[0] = (_Float16)v.x; pk.h[1] = (_Float16)v.y;
  pk.h[2] = (_Float16)v.z; pk.h[3] = (_Float16)v.w;
  *(uint2*)(d + i) = pk.u;
}

// ---------------------------------------------------------------------------
// GEMM core: BMx128 tile (BM=64 or 128), BK=32, 3-buffer LDS pipeline with
// counted vmcnt and ONE raw barrier per k-step. 4 waves, each (BM/2)x64.
// EPI: 0 = plain C (+bias); 1 = qkv routing (rope q/k row-major, V
// transposed tile-major swizzled).
// ---------------------------------------------------------------------------
template<int BM, int EPI, typename OutT>
__global__ __launch_bounds__(256)
void gemm_p3(const _Float16* __restrict__ A, const _Float16* __restrict__ B,
             const float* __restrict__ bias, const float2* __restrict__ tab,
             OutT* __restrict__ C, _Float16* __restrict__ Ko,
             _Float16* __restrict__ Vo, int N) {
  constexpr int K = DM;
  constexpr int MFR = BM / 32;          // A-frags per wave
  constexpr int ACH = BM * 4 / 256;     // A gload_lds per thread per stage
  constexpr int NOPS = ACH + 2;         // total gloads per stage per thread
  __shared__ _Float16 As[3][BM * 32];
  __shared__ _Float16 Bs[3][128 * 32];

  const int t = threadIdx.x, lane = t & 63, wv = t >> 6;
  const int l15 = lane & 15, l4 = lane >> 4;
  const int wr = wv >> 1, wc = wv & 1;
  const int bm = blockIdx.y * BM, bn = blockIdx.x * 128;

  auto stage = [&](int buf, int k0) {
    #pragma unroll
    for (int i = 0; i < ACH; ++i) {
      int c = t + i * 256;
      GLOAD_LDS16(A + (size_t)(bm + (c >> 2)) * K + k0 + (c & 3) * 8,
                  (char*)&As[buf][(i * 256 + wv * 64) * 8]);
    }
    #pragma unroll
    for (int i = 0; i < 2; ++i) {
      int c = t + i * 256;
      GLOAD_LDS16(B + (size_t)(bn + (c >> 2)) * K + k0 + (c & 3) * 8,
                  (char*)&Bs[buf][(i * 256 + wv * 64) * 8]);
    }
  };

  f32x4 acc[MFR][4] = {};
  stage(0, 0);
  stage(1, 32);

  const int nk = K / 32;
  for (int s = 0; s < nk; ++s) {
    int cur = s % 3;
    // wait own stage(s) done; stage(s+1)'s NOPS ops stay in flight
    if (s + 1 < nk) {
      if constexpr (NOPS == 3) asm volatile("s_waitcnt vmcnt(3)" ::: "memory");
      else                     asm volatile("s_waitcnt vmcnt(4)" ::: "memory");
    } else {
      asm volatile("s_waitcnt vmcnt(0)" ::: "memory");
    }
    __builtin_amdgcn_s_barrier();       // all waves' stage(s) published;
    __builtin_amdgcn_sched_barrier(0);  // all done reading buf[(s-1)%3]
    if (s + 2 < nk) stage((s + 2) % 3, (s + 2) * 32);

    half8 af[MFR], bf[4];
    #pragma unroll
    for (int mf = 0; mf < MFR; ++mf)
      af[mf] = *(const half8*)&As[cur][(wr * (BM / 2) + mf * 16 + l15) * 32 + l4 * 8];
    #pragma unroll
    for (int nf = 0; nf < 4; ++nf)
      bf[nf] = *(const half8*)&Bs[cur][(wc * 64 + nf * 16 + l15) * 32 + l4 * 8];
    __builtin_amdgcn_s_setprio(1);
    #pragma unroll
    for (int mf = 0; mf < MFR; ++mf)
      #pragma unroll
      for (int nf = 0; nf < 4; ++nf)
        acc[mf][nf] = __builtin_amdgcn_mfma_f32_16x16x32_f16(
            af[mf], bf[nf], acc[mf][nf], 0, 0, 0);
    __builtin_amdgcn_s_setprio(0);
  }

  float bv[4];
  #pragma unroll
  for (int nf = 0; nf < 4; ++nf) bv[nf] = bias[bn + wc * 64 + nf * 16 + l15];

  if (EPI == 0) {
    #pragma unroll
    for (int mf = 0; mf < MFR; ++mf)
      #pragma unroll
      for (int r = 0; r < 4; ++r) {
        int row = bm + wr * (BM / 2) + mf * 16 + l4 * 4 + r;
        OutT* cr = C + (size_t)row * N + bn + wc * 64 + l15;
        cr[0]  = (OutT)(acc[mf][0][r] + bv[0]);
        cr[16] = (OutT)(acc[mf][1][r] + bv[1]);
        cr[32] = (OutT)(acc[mf][2][r] + bv[2]);
        cr[48] = (OutT)(acc[mf][3][r] + bv[3]);
      }
    return;
  }

  const int sec = bn >> 10;  // 0=q, 1=k, 2=v
  if (sec < 2) {
    // q and k: RoPE, row-major coalesced stores (k: no QSCALE)
    OutT* dst = (sec == 0) ? C : (OutT*)Ko;
    #pragma unroll
    for (int mf = 0; mf < MFR; ++mf)
      #pragma unroll
      for (int r = 0; r < 4; ++r) {
        int row = bm + wr * (BM / 2) + mf * 16 + l4 * 4 + r;
        float v0 = acc[mf][0][r] + bv[0];
        float v1 = acc[mf][1][r] + bv[1];
        float v2 = acc[mf][2][r] + bv[2];
        float v3 = acc[mf][3][r] + bv[3];
        float2 cs0 = tab[row * 32 + l15];
        float2 cs1 = tab[row * 32 + 16 + l15];
        float a0 = v0 * cs0.x - v2 * cs0.y;
        float a2 = v2 * cs0.x + v0 * cs0.y;
        float a1 = v1 * cs1.x - v3 * cs1.y;
        float a3 = v3 * cs1.x + v1 * cs1.y;
        if (sec == 0) { a0 *= QSCALE; a1 *= QSCALE; a2 *= QSCALE; a3 *= QSCALE; }
        OutT* cr = dst + (size_t)row * DM + (bn & 1023) + wc * 64 + l15;
        cr[0]  = (OutT)a0; cr[16] = (OutT)a1;
        cr[32] = (OutT)a2; cr[48] = (OutT)a3;
      }
  } else {
    // V: transposed tile-major swizzled [h][kseg][d][chunk^(d&7)][8]
    const int hh = ((bn - 2048) >> 6) + wc;
    #pragma unroll
    for (int mf = 0; mf < MFR; ++mf) {
      int row0 = bm + wr * (BM / 2) + mf * 16 + l4 * 4;
      int kk0 = row0 & 63, kseg = row0 >> 6;
      #pragma unroll
      for (int nf = 0; nf < 4; ++nf) {
        int d = nf * 16 + l15;
        union { _Float16 hh4[4]; uint2 u; } pk;
        #pragma unroll
        for (int r = 0; r < 4; ++r)
          pk.hh4[r] = (_Float16)(acc[mf][nf][r] + bv[nf]);
        size_t off = ((size_t)(hh * 32 + kseg) * 64 + d) * 64 +
                     (((kk0 >> 3) ^ (d & 7)) * 8) + (kk0 & 7);
        *(uint2*)(Vo + off) = pk.u;
      }
    }
  }
}

// ---------------------------------------------------------------------------
// MFMA flash attention (best config, R14): 8 waves / 128 q-rows per block.
// All-x32 permuted-key pipeline: packed exp2(P) registers feed 16x16x32 PV
// directly (zero P data movement). Max-free exp2 softmax; pure-DMA
// double-buffered K/V; one barrier per tile; DMA issued after the barrier.
// ---------------------------------------------------------------------------
__global__ __launch_bounds__(512)
void attn_f16(const _Float16* __restrict__ Qg, const _Float16* __restrict__ Kg,
              const _Float16* __restrict__ Vg, _Float16* __restrict__ poA,
              _Float16* __restrict__ po3, float* __restrict__ pl) {
  __shared__ _Float16 Kl[2][64 * 64];   // [kk][chunk p at p^HK(kk)]
  __shared__ _Float16 Vt[2][64 * 64];   // [d][chunk p at p^(d&7)]

  const int t = threadIdx.x, lane = t & 63, wv = t >> 6;  // wv in 0..7
  const int l15 = lane & 15, l4 = lane >> 4;
  const int bid = blockIdx.x;
  const int c = bid & 63, qb = bid >> 6;   // same (h,z) => same XCD (64%8==0)
  const int h = c & 15, z = c >> 4;        // z in 0..3
  const int q0 = qb * 128;
  const int seg0 = z * (SEQ / NSPLIT / 64);

  const _Float16* Qp = Qg + h * HD;
  const _Float16* Kp = Kg + h * HD;                 // row-major [s][1024]
  const _Float16* Vbase = Vg + (size_t)h * 32 * 4096;

  half8 qf[2];
  {
    const _Float16* qrow = Qp + (size_t)(q0 + wv * 16 + l15) * DM;
    qf[0] = *(const half8*)(qrow + l4 * 8);
    qf[1] = *(const half8*)(qrow + 32 + l4 * 8);
  }

  // per-lane K source offset: chunk c=t -> row kk=t>>3, p=t&7,
  // src col chunk = p ^ HK(kk), HK = bits{0,1,3} of kk
  int koff;
  {
    int kk = t >> 3, p = t & 7;
    int hkk = (kk & 3) | ((kk >> 1) & 4);
    koff = kk * DM + ((p ^ hkk) * 8);
  }

  auto issueKV = [&](int buf, int seg) {
    const _Float16* ks = Kp + (size_t)seg * 64 * DM;
    const _Float16* vs = Vbase + (size_t)seg * 4096;
    GLOAD_LDS16(ks + koff,          (char*)&Kl[buf][(wv * 64) * 8]);
    GLOAD_LDS16(vs + (size_t)t * 8, (char*)&Vt[buf][(wv * 64) * 8]);
  };

  f32x4 lacc = {0.f, 0.f, 0.f, 0.f};
  f32x4 o[4] = {};   // O^T: o[nf][r] = O[d = nf*16 + l4*4 + r][q = l15]

  const int hk = (l15 & 3) | (((l15 >> 2) & 1) << 2);  // HK(kappa), m-indep
  const int krow = 8 * (l15 >> 2) + (l15 & 3);         // kappa_m base

  issueKV(0, seg0);

  const int NT = SEQ / NSPLIT / 64;
  #pragma unroll 2
  for (int tt = 0; tt < NT; ++tt) {
    const int cur = tt & 1;
    asm volatile("s_waitcnt vmcnt(0)" ::: "memory");
    __builtin_amdgcn_s_barrier();
    __builtin_amdgcn_sched_barrier(0);
    if (tt + 1 < NT) issueKV(cur ^ 1, seg0 + tt + 1);  // covered by compute(t)

    // S^T = K . Q^T with permuted key rows (exp2 domain)
    f32x4 sT[4] = {};
    __builtin_amdgcn_s_setprio(1);
    #pragma unroll
    for (int ds = 0; ds < 2; ++ds)
      #pragma unroll
      for (int m = 0; m < 4; ++m) {
        int kappa = 32 * (m >> 1) + 4 * (m & 1) + krow;
        int cb = ds * 4 + l4;
        half8 kf = *(const half8*)((char*)Kl[cur] + kappa * 128 +
                                   ((cb ^ hk) * 16));
        sT[m] = __builtin_amdgcn_mfma_f32_16x16x32_f16(kf, qf[ds], sT[m], 0, 0, 0);
      }
    __builtin_amdgcn_s_setprio(0);

    // P = exp2(S); packed pairs form the PV B-frags directly
    half8 pB[2];
    #pragma unroll
    for (int s2 = 0; s2 < 2; ++s2) {
      union { fp16x2 h2[4]; half8 v; } pu;
      #pragma unroll
      for (int mh = 0; mh < 2; ++mh) {
        int m = s2 * 2 + mh;
        f32x4 p;
        #pragma unroll
        for (int r = 0; r < 4; ++r) p[r] = exp2f(sT[m][r]);
        lacc += p;
        pu.h2[mh * 2 + 0] = __builtin_amdgcn_cvt_pkrtz(p[0], p[1]);
        pu.h2[mh * 2 + 1] = __builtin_amdgcn_cvt_pkrtz(p[2], p[3]);
      }
      pB[s2] = pu.v;
    }

    // PV: O^T[d][q] += V^T[d][k] . P[k][q], 16x16x32, b128 V reads
    __builtin_amdgcn_s_setprio(1);
    #pragma unroll
    for (int s2 = 0; s2 < 2; ++s2)
      #pragma unroll
      for (int nf = 0; nf < 4; ++nf) {
        half8 va = *(const half8*)((char*)Vt[cur] + (nf * 16 + l15) * 128 +
                                   (((s2 * 4 + l4) ^ (l15 & 7)) * 16));
        o[nf] = __builtin_amdgcn_mfma_f32_16x16x32_f16(va, pB[s2], o[nf], 0, 0, 0);
      }
    __builtin_amdgcn_s_setprio(0);
  }

  // epilogue: unnormalized partial O (transposed acc -> row=q stores) + l
  float lv = (lacc[0] + lacc[1]) + (lacc[2] + lacc[3]);
  lv += __shfl_xor(lv, 16);
  lv += __shfl_xor(lv, 32);
  _Float16* pz = (z < 3) ? (poA + (size_t)z * SEQ * DM) : po3;
  {
    int row = q0 + wv * 16 + l15;
    _Float16* pr = pz + (size_t)row * DM + h * HD + l4 * 4;
    #pragma unroll
    for (int nf = 0; nf < 4; ++nf) {
      union { fp16x2 h2[2]; uint2 u; } ou;
      ou.h2[0] = __builtin_amdgcn_cvt_pkrtz(o[nf][0], o[nf][1]);
      ou.h2[1] = __builtin_amdgcn_cvt_pkrtz(o[nf][2], o[nf][3]);
      *(uint2*)(pr + nf * 16) = ou.u;
    }
  }
  if (l4 == 0) {
    int q = q0 + wv * 16 + l15;
    pl[(z * NH + h) * SEQ + q] = lv;
  }
}

// ---------------------------------------------------------------------------
// Combine the 4 partials: O = (o0+o1+o2+o3) / (l0+l1+l2+l3).
// po3 aliases ctx: each thread reads its 8 elems before writing them -> safe.
// ---------------------------------------------------------------------------
__global__ __launch_bounds__(256)
void merge4(const _Float16* __restrict__ poA, const _Float16* __restrict__ po3,
            const float* __restrict__ pl, _Float16* __restrict__ ctx) {
  int e = (blockIdx.x * 256 + threadIdx.x) * 8;   // over SEQ*DM
  int s = e >> 10, h = (e & 1023) >> 6;
  int idx = h * SEQ + s;
  float L = pl[idx] + pl[NH * SEQ + idx] + pl[2 * NH * SEQ + idx] +
            pl[3 * NH * SEQ + idx];
  float inv = 1.0f / L;
  half8 a = *(const half8*)(poA + e);
  half8 b = *(const half8*)(poA + (size_t)SEQ * DM + e);
  half8 cc = *(const half8*)(poA + 2 * (size_t)SEQ * DM + e);
  half8 d = *(const half8*)(po3 + e);
  half8 o;
  #pragma unroll
  for (int j = 0; j < 8; ++j)
    o[j] = (_Float16)((((float)a[j] + (float)b[j]) +
                       ((float)cc[j] + (float)d[j])) * inv);
  *(half8*)(ctx + e) = o;
}

// ---------------------------------------------------------------------------
extern "C" void kernel_launch(void* const* d_in, const int* in_sizes, int n_in,
                              void* d_out, int out_size, void* d_ws, size_t ws_size,
                              hipStream_t stream) {
  const float* query = (const float*)d_in[0];
  const float* qkv_w = (const float*)d_in[3];
  const float* qkv_b = (const float*)d_in[4];
  const float* out_w = (const float*)d_in[5];
  const float* out_b = (const float*)d_in[6];
  float* out = (float*)d_out;

  char* ws = (char*)d_ws;
  _Float16* Aq   = (_Float16*)ws;                       // [0, 4 MiB)   dead after qkv
  _Float16* Wqkv = (_Float16*)(ws + (4u << 20));        // [4, 10 MiB)  dead after qkv
  _Float16* Qb   = (_Float16*)(ws + (12u << 20));       // [12, 16 MiB)
  _Float16* Kb   = (_Float16*)(ws + (16u << 20));       // [16, 20 MiB) row-major roped
  _Float16* Vb   = (_Float16*)(ws + (20u << 20));       // [20, 24 MiB) tile-major
  _Float16* ctx  = (_Float16*)(ws + (24u << 20));       // [24, 28 MiB)
  float2*   tab  = (float2*)(ws + (28u << 20));         // [28, 28.5 MiB)
  _Float16* Wout = (_Float16*)(ws + (28u << 20) + (512u << 10)); // [28.5, 30.5)
  float*    pl   = (float*)(ws + (30u << 20) + (512u << 10));    // [30.5, 31)
  // partials: z=0..2 in the dead [0,12) region; z=3 aliases ctx
  _Float16* poA  = (_Float16*)ws;                       // [0, 12 MiB)
  _Float16* po3  = ctx;                                 // [24, 28 MiB)

  cvt3<<<6400, 256, 0, stream>>>(query, qkv_w, out_w, Aq, Wqkv, Wout, tab,
                                 SEQ * DM, TRI * DM);

  gemm_p3<128, 1, _Float16><<<dim3(TRI / 128, SEQ / 128), 256, 0, stream>>>(
      Aq, Wqkv, qkv_b, tab, Qb, Kb, Vb, TRI);

  attn_f16<<<(SEQ / 128) * NH * NSPLIT, 512, 0, stream>>>(
      Qb, Kb, Vb, poA, po3, pl);

  merge4<<<SEQ * DM / 8 / 256, 256, 0, stream>>>(poA, po3, pl, ctx);

  gemm_p3<64, 0, float><<<dim3(DM / 128, SEQ / 64), 256, 0, stream>>>(
      ctx, Wout, out_b, nullptr, out, nullptr, nullptr, DM);
}